// Round 2
// baseline (1054.549 us; speedup 1.0000x reference)
//
#include <hip/hip_runtime.h>
#include <cstdint>
#include <cstddef>

// ---------------------------------------------------------------------------
// Llama decoder layer, MI355X.  B=1, T=2048, D=2048, FF=8192, NH=32, NKV=8,
// HD=64.  bf16 MFMA (16x16x32), fp32 accumulate.
// out = h2 + mlp(h2) + x0, where h2 = rms(h1 + attn(h1)), h1 = rms(x0).
//
// Workspace budget (peak 164 MB; round-0 crash was d_ws overflow at 288 MB):
//   [0,8)    wq_t      [8,10) wk_t   [10,12) wv_t   [12,20) wo_t
//   [20,52)  wg_t      [52,84) wu_t
//   [84,92)  h1_b      [92,100) h2_b
//   [100,132) gate/act (bf16, in-place SwiGLU); [100,116) doubles as x2_f
//   [132,164) attn scratch {q_b 8, k_b 2, vt_b 2, y_b 8} then wd_t (32)
// ---------------------------------------------------------------------------

typedef __attribute__((ext_vector_type(8))) short short8;   // 8 x bf16
typedef __attribute__((ext_vector_type(4))) float f32x4;

typedef __attribute__((address_space(1))) const void gvoid_t;  // global
typedef __attribute__((address_space(3))) void lvoid_t;        // LDS

__device__ inline unsigned short f2b(float f) {   // fp32 -> bf16 (RNE)
  unsigned int u = __float_as_uint(f);
  u += 0x7fffu + ((u >> 16) & 1u);
  return (unsigned short)(u >> 16);
}
__device__ inline float b2f(unsigned short s) {
  return __uint_as_float((unsigned int)s << 16);
}

// ---------------------------------------------------------------------------
// Cast + transpose:  W fp32 [R][ldW]  ->  Wt bf16 [ldW-cols][R]
// 32x32 tiles through LDS (pad 36 to break bank alignment).
// ---------------------------------------------------------------------------
__global__ __launch_bounds__(256) void transpose_cast(
    const float* __restrict__ W, unsigned short* __restrict__ Wt,
    int R, int ldW) {
  __shared__ unsigned short s[32 * 36];
  const int r0 = blockIdx.y * 32, c0 = blockIdx.x * 32;
  const int tr = threadIdx.x >> 3, tc = (threadIdx.x & 7) << 2;
  const float4 v = *(const float4*)(W + (size_t)(r0 + tr) * ldW + c0 + tc);
  s[tr * 36 + tc + 0] = f2b(v.x);
  s[tr * 36 + tc + 1] = f2b(v.y);
  s[tr * 36 + tc + 2] = f2b(v.z);
  s[tr * 36 + tc + 3] = f2b(v.w);
  __syncthreads();
  ushort4 o;
  o.x = s[(tc + 0) * 36 + tr];
  o.y = s[(tc + 1) * 36 + tr];
  o.z = s[(tc + 2) * 36 + tr];
  o.w = s[(tc + 3) * 36 + tr];
  *(ushort4*)(Wt + (size_t)(c0 + tr) * R + r0 + tc) = o;
}

// ---------------------------------------------------------------------------
// RMSNorm (one block per row of 2048) -> bf16.
// ---------------------------------------------------------------------------
__global__ __launch_bounds__(256) void rmsnorm(
    const float* __restrict__ X, const float* __restrict__ g,
    unsigned short* __restrict__ ob) {
  const int row = blockIdx.x;
  const float* x = X + (size_t)row * 2048;
  float ss = 0.f;
  for (int i = threadIdx.x; i < 2048; i += 256) { float v = x[i]; ss += v * v; }
  for (int off = 32; off; off >>= 1) ss += __shfl_down(ss, off, 64);
  __shared__ float red[4];
  if ((threadIdx.x & 63) == 0) red[threadIdx.x >> 6] = ss;
  __syncthreads();
  const float tot = red[0] + red[1] + red[2] + red[3];
  const float r = rsqrtf(tot * (1.f / 2048.f) + 1e-5f);
  for (int i = threadIdx.x; i < 2048; i += 256)
    ob[(size_t)row * 2048 + i] = f2b(x[i] * g[i] * r);
}

// ---------------------------------------------------------------------------
// GEMM: acc[M][N] = A[M][K] * Bt[N][K]^T   (bf16 in, fp32 acc)
// 128x128 tile, BK=32, 4 waves (2x2 of 64x64), global_load_lds staging.
// Epilogues:
//   1: Cf = acc + b2f(add1b)                       (wo + residual h1)
//   2: Cf = acc + b2f(add1b) + add2                (down + h2 + x0)
//   3: Cb = f2b( silu(b2f(add1b)) * acc )          (up; in-place over gate)
//   4: Cb = f2b(acc)                               (gate)
//   5: Cb = f2b(rope(acc))                         (q/k; pair via shfl_xor 1)
//   6: Cb[col*Tld + row] = f2b(acc)                (v, transposed store)
// ---------------------------------------------------------------------------
__global__ __launch_bounds__(256, 2) void gemm_bt(
    const unsigned short* __restrict__ A, const unsigned short* __restrict__ Bt,
    float* Cf, unsigned short* Cb,
    const unsigned short* add1b, const float* add2,
    int N, int K, int epi, int Tld) {
  __shared__ unsigned short As[128 * 32];
  __shared__ unsigned short Bs[128 * 32];
  const int tid = threadIdx.x;
  const int wave = tid >> 6, lane = tid & 63;
  const int quad = lane >> 4, l16 = lane & 15;
  const int m0 = blockIdx.y * 128, n0 = blockIdx.x * 128;
  const int wr = (wave >> 1) * 64, wc = (wave & 1) * 64;

  f32x4 acc[4][4] = {};

  for (int k0 = 0; k0 < K; k0 += 32) {
    // Direct global->LDS, 16B/lane; LDS dest = wave-uniform base + lane*16.
#pragma unroll
    for (int p = 0; p < 2; ++p) {
      const int idx = p * 256 + tid;
      const int row = idx >> 2, q4 = idx & 3;
      const unsigned short* gA = A + (size_t)(m0 + row) * K + k0 + q4 * 8;
      const unsigned short* gB = Bt + (size_t)(n0 + row) * K + k0 + q4 * 8;
      unsigned short* lA = As + (size_t)(p * 256 + wave * 64) * 8;
      unsigned short* lB = Bs + (size_t)(p * 256 + wave * 64) * 8;
      __builtin_amdgcn_global_load_lds((gvoid_t*)gA, (lvoid_t*)lA, 16, 0, 0);
      __builtin_amdgcn_global_load_lds((gvoid_t*)gB, (lvoid_t*)lB, 16, 0, 0);
    }
    __syncthreads();

    short8 af[4], bf[4];
#pragma unroll
    for (int i = 0; i < 4; ++i)
      af[i] = *(const short8*)(As + (wr + i * 16 + l16) * 32 + quad * 8);
#pragma unroll
    for (int j = 0; j < 4; ++j)
      bf[j] = *(const short8*)(Bs + (wc + j * 16 + l16) * 32 + quad * 8);
#pragma unroll
    for (int i = 0; i < 4; ++i)
#pragma unroll
      for (int j = 0; j < 4; ++j)
        acc[i][j] = __builtin_amdgcn_mfma_f32_16x16x32_bf16(af[i], bf[j],
                                                            acc[i][j], 0, 0, 0);
    __syncthreads();
  }

  // C/D layout: col = lane&15, row = quad*4 + reg.
  if (epi == 6) {   // transposed V store, rows contiguous -> ushort4
#pragma unroll
    for (int i = 0; i < 4; ++i)
#pragma unroll
      for (int j = 0; j < 4; ++j) {
        const int row = m0 + wr + i * 16 + quad * 4;
        const int col = n0 + wc + j * 16 + l16;
        ushort4 o;
        o.x = f2b(acc[i][j][0]); o.y = f2b(acc[i][j][1]);
        o.z = f2b(acc[i][j][2]); o.w = f2b(acc[i][j][3]);
        *(ushort4*)(Cb + (size_t)col * Tld + row) = o;
      }
    return;
  }

#pragma unroll
  for (int i = 0; i < 4; ++i)
#pragma unroll
    for (int j = 0; j < 4; ++j) {
      const int rowb = m0 + wr + i * 16 + quad * 4;
      const int col = n0 + wc + j * 16 + l16;
      float invf = 0.f, sgn = 0.f;
      if (epi == 5) {
        const int ip = (col & 63) >> 1;            // rope pair index
        invf = __expf(-(float)ip * 0.28782313662f); // 10000^(-ip/32)
        sgn = (col & 1) ? 1.f : -1.f;
      }
#pragma unroll
      for (int r = 0; r < 4; ++r) {
        const size_t idx = (size_t)(rowb + r) * N + col;
        const float v = acc[i][j][r];
        const float p = __shfl_xor(v, 1, 64);      // rope partner (epi 5)
        if (epi == 1) {
          Cf[idx] = v + b2f(add1b[idx]);
        } else if (epi == 2) {
          Cf[idx] = v + b2f(add1b[idx]) + add2[idx];
        } else if (epi == 3) {
          const float gt = b2f(add1b[idx]);
          Cb[idx] = f2b(gt / (1.f + __expf(-gt)) * v);
        } else if (epi == 4) {
          Cb[idx] = f2b(v);
        } else {  // 5: rope
          float sn, cs;
          __sincosf((float)(rowb + r) * invf, &sn, &cs);
          Cb[idx] = f2b(v * cs + sgn * p * sn);
        }
      }
    }
}

// ---------------------------------------------------------------------------
// Flash attention, causal, GQA (kv head = h>>2).  One wave per
// (head, 16-row Q tile); 32-key tiles; online softmax; P C-layout -> A-layout
// via 1KB LDS round trip.
// Qb [T][2048] roped bf16; Kb [T][512] roped bf16; Vt [512][T] bf16.
// ---------------------------------------------------------------------------
__global__ __launch_bounds__(64) void flash_attn(
    const unsigned short* __restrict__ Qb, const unsigned short* __restrict__ Kb,
    const unsigned short* __restrict__ Vt, unsigned short* __restrict__ Y,
    int T) {
  __shared__ unsigned short P[16 * 32];
  const int lane = threadIdx.x;
  const int quad = lane >> 4, l16 = lane & 15;
  const int h = blockIdx.y, qt = blockIdx.x;
  const int kvh = h >> 2;
  const int qbase = qt * 16;

  short8 aQ[2];
#pragma unroll
  for (int c = 0; c < 2; ++c)
    aQ[c] = *(const short8*)(Qb + (size_t)(qbase + l16) * 2048 + h * 64 +
                             c * 32 + quad * 8);

  float m_i[4], l_i[4];
  f32x4 Oacc[4] = {};
#pragma unroll
  for (int r = 0; r < 4; ++r) { m_i[r] = -1e30f; l_i[r] = 0.f; }

  const int lastT = (qbase + 15) >> 5;
  for (int jt = 0; jt <= lastT; ++jt) {
    f32x4 S[2];
#pragma unroll
    for (int s = 0; s < 2; ++s) {
      const size_t kr = (size_t)(jt * 32 + s * 16 + l16) * 512 + kvh * 64;
      short8 bK0 = *(const short8*)(Kb + kr + quad * 8);
      short8 bK1 = *(const short8*)(Kb + kr + 32 + quad * 8);
      f32x4 z = {};
      z = __builtin_amdgcn_mfma_f32_16x16x32_bf16(aQ[0], bK0, z, 0, 0, 0);
      z = __builtin_amdgcn_mfma_f32_16x16x32_bf16(aQ[1], bK1, z, 0, 0, 0);
      S[s] = z;
    }
    float tmax[4];
#pragma unroll
    for (int r = 0; r < 4; ++r) {
      const int qrow = qbase + quad * 4 + r;
#pragma unroll
      for (int s = 0; s < 2; ++s) {
        const int key = jt * 32 + s * 16 + l16;
        float v = S[s][r] * 0.125f;
        if (key > qrow) v = -1e30f;
        S[s][r] = v;
      }
      tmax[r] = fmaxf(S[0][r], S[1][r]);
    }
#pragma unroll
    for (int off = 1; off < 16; off <<= 1)
#pragma unroll
      for (int r = 0; r < 4; ++r)
        tmax[r] = fmaxf(tmax[r], __shfl_xor(tmax[r], off, 64));

    float alpha[4], rsum[4];
#pragma unroll
    for (int r = 0; r < 4; ++r) {
      const float mn = fmaxf(m_i[r], tmax[r]);
      alpha[r] = __expf(m_i[r] - mn);
      m_i[r] = mn;
      const float p0 = __expf(S[0][r] - mn);
      const float p1 = __expf(S[1][r] - mn);
      S[0][r] = p0; S[1][r] = p1;
      rsum[r] = p0 + p1;
    }
#pragma unroll
    for (int off = 1; off < 16; off <<= 1)
#pragma unroll
      for (int r = 0; r < 4; ++r)
        rsum[r] += __shfl_xor(rsum[r], off, 64);
#pragma unroll
    for (int r = 0; r < 4; ++r) l_i[r] = l_i[r] * alpha[r] + rsum[r];

    __syncthreads();
#pragma unroll
    for (int s = 0; s < 2; ++s)
#pragma unroll
      for (int r = 0; r < 4; ++r)
        P[(quad * 4 + r) * 32 + s * 16 + l16] = f2b(S[s][r]);
    __syncthreads();
    const short8 aP = *(const short8*)(P + l16 * 32 + quad * 8);

#pragma unroll
    for (int c = 0; c < 4; ++c)
#pragma unroll
      for (int r = 0; r < 4; ++r) Oacc[c][r] *= alpha[r];
#pragma unroll
    for (int c = 0; c < 4; ++c) {
      const short8 bV = *(const short8*)(
          Vt + (size_t)(kvh * 64 + c * 16 + l16) * T + jt * 32 + quad * 8);
      Oacc[c] = __builtin_amdgcn_mfma_f32_16x16x32_bf16(aP, bV, Oacc[c], 0, 0, 0);
    }
  }

#pragma unroll
  for (int c = 0; c < 4; ++c)
#pragma unroll
    for (int r = 0; r < 4; ++r) {
      const float v = Oacc[c][r] / l_i[r];
      Y[(size_t)(qbase + quad * 4 + r) * 2048 + h * 64 + c * 16 + l16] = f2b(v);
    }
}

// ---------------------------------------------------------------------------
extern "C" void kernel_launch(void* const* d_in, const int* in_sizes, int n_in,
                              void* d_out, int out_size, void* d_ws,
                              size_t ws_size, hipStream_t stream) {
  const float* x  = (const float*)d_in[0];
  const float* g1 = (const float*)d_in[1];
  const float* wq = (const float*)d_in[2];
  const float* wk = (const float*)d_in[3];
  const float* wv = (const float*)d_in[4];
  const float* wo = (const float*)d_in[5];
  const float* g2 = (const float*)d_in[6];
  const float* wg = (const float*)d_in[7];
  const float* wu = (const float*)d_in[8];
  const float* wd = (const float*)d_in[9];
  float* out = (float*)d_out;

  const int T = 2048, Dm = 2048, FF = 8192;
  char* ws = (char*)d_ws;
  const size_t MB = (size_t)1 << 20;

  unsigned short* wq_t = (unsigned short*)(ws + 0 * MB);    // 8 MB
  unsigned short* wk_t = (unsigned short*)(ws + 8 * MB);    // 2 MB
  unsigned short* wv_t = (unsigned short*)(ws + 10 * MB);   // 2 MB
  unsigned short* wo_t = (unsigned short*)(ws + 12 * MB);   // 8 MB
  unsigned short* wg_t = (unsigned short*)(ws + 20 * MB);   // 32 MB
  unsigned short* wu_t = (unsigned short*)(ws + 52 * MB);   // 32 MB
  unsigned short* h1_b = (unsigned short*)(ws + 84 * MB);   // 8 MB
  unsigned short* h2_b = (unsigned short*)(ws + 92 * MB);   // 8 MB
  float*          x2_f = (float*)(ws + 100 * MB);           // 16 MB (dies early)
  unsigned short* gate = (unsigned short*)(ws + 100 * MB);  // 32 MB (act in-place)
  unsigned short* q_b  = (unsigned short*)(ws + 132 * MB);  // 8 MB
  unsigned short* k_b  = (unsigned short*)(ws + 140 * MB);  // 2 MB
  unsigned short* vt_b = (unsigned short*)(ws + 142 * MB);  // 2 MB
  unsigned short* y_b  = (unsigned short*)(ws + 144 * MB);  // 8 MB
  unsigned short* wd_t = (unsigned short*)(ws + 132 * MB);  // 32 MB (after attn)
  // peak: 164 MB

  // 1. Weight cast+transpose (wd deferred until its region is free).
  transpose_cast<<<dim3(64, 64), 256, 0, stream>>>(wq, wq_t, Dm, Dm);
  transpose_cast<<<dim3(16, 64), 256, 0, stream>>>(wk, wk_t, Dm, 512);
  transpose_cast<<<dim3(16, 64), 256, 0, stream>>>(wv, wv_t, Dm, 512);
  transpose_cast<<<dim3(64, 64), 256, 0, stream>>>(wo, wo_t, Dm, Dm);
  transpose_cast<<<dim3(256, 64), 256, 0, stream>>>(wg, wg_t, Dm, FF);
  transpose_cast<<<dim3(256, 64), 256, 0, stream>>>(wu, wu_t, Dm, FF);

  // 2. h1 = rms(x0)
  rmsnorm<<<T, 256, 0, stream>>>(x, g1, h1_b);

  // 3. Q/K/V projections; rope fused (epi 5), V transposed store (epi 6).
  gemm_bt<<<dim3(16, 16), 256, 0, stream>>>(h1_b, wq_t, nullptr, q_b, nullptr,
                                            nullptr, Dm, Dm, 5, 0);
  gemm_bt<<<dim3(4, 16), 256, 0, stream>>>(h1_b, wk_t, nullptr, k_b, nullptr,
                                           nullptr, 512, Dm, 5, 0);
  gemm_bt<<<dim3(4, 16), 256, 0, stream>>>(h1_b, wv_t, nullptr, vt_b, nullptr,
                                           nullptr, 512, Dm, 6, T);

  // 4. Attention.
  flash_attn<<<dim3(T / 16, 32), 64, 0, stream>>>(q_b, k_b, vt_b, y_b, T);

  // 5. x2 = h1 + y @ wo  (epi 1, bf16 residual).
  gemm_bt<<<dim3(16, 16), 256, 0, stream>>>(y_b, wo_t, x2_f, nullptr, h1_b,
                                            nullptr, Dm, Dm, 1, 0);

  // 6. wd transpose into the now-dead attention scratch.
  transpose_cast<<<dim3(64, 256), 256, 0, stream>>>(wd, wd_t, FF, Dm);

  // 7. h2 = rms(x2)
  rmsnorm<<<T, 256, 0, stream>>>(x2_f, g2, h2_b);

  // 8. MLP: gate (epi 4, bf16), then up fused with silu in-place (epi 3).
  gemm_bt<<<dim3(64, 16), 256, 0, stream>>>(h2_b, wg_t, nullptr, gate, nullptr,
                                            nullptr, FF, Dm, 4, 0);
  gemm_bt<<<dim3(64, 16), 256, 0, stream>>>(h2_b, wu_t, nullptr, gate, gate,
                                            nullptr, FF, Dm, 3, 0);

  // 9. out = act @ wd + h2 + x0  (epi 2).
  gemm_bt<<<dim3(16, 16), 256, 0, stream>>>(gate, wd_t, out, nullptr, h2_b, x,
                                            Dm, FF, 2, 0);
}

// Round 3
// 989.293 us; speedup vs baseline: 1.0660x; 1.0660x over previous
//
#include <hip/hip_runtime.h>
#include <cstdint>
#include <cstddef>

// ---------------------------------------------------------------------------
// Llama decoder layer, MI355X.  B=1, T=2048, D=2048, FF=8192, NH=32, NKV=8,
// HD=64.  bf16 MFMA (16x16x32), fp32 accumulate.
// out = h2 + mlp(h2) + x0, where h2 = rms(h1 + attn(h1)), h1 = rms(x0).
//
// Workspace peak 164 MB (same layout as round 2, which passed).
// Round 3 change: flash_attn rewritten flash-decoding style (4 waves/block
// splitting the key range, 128-key chunks, LDS merge) — was 240 us
// latency-bound (MfmaUtil 2.9%).
// ---------------------------------------------------------------------------

typedef __attribute__((ext_vector_type(8))) short short8;   // 8 x bf16
typedef __attribute__((ext_vector_type(4))) float f32x4;

typedef __attribute__((address_space(1))) const void gvoid_t;  // global
typedef __attribute__((address_space(3))) void lvoid_t;        // LDS

__device__ inline unsigned short f2b(float f) {   // fp32 -> bf16 (RNE)
  unsigned int u = __float_as_uint(f);
  u += 0x7fffu + ((u >> 16) & 1u);
  return (unsigned short)(u >> 16);
}
__device__ inline float b2f(unsigned short s) {
  return __uint_as_float((unsigned int)s << 16);
}

// ---------------------------------------------------------------------------
// Cast + transpose:  W fp32 [R][ldW]  ->  Wt bf16 [ldW-cols][R]
// ---------------------------------------------------------------------------
__global__ __launch_bounds__(256) void transpose_cast(
    const float* __restrict__ W, unsigned short* __restrict__ Wt,
    int R, int ldW) {
  __shared__ unsigned short s[32 * 36];
  const int r0 = blockIdx.y * 32, c0 = blockIdx.x * 32;
  const int tr = threadIdx.x >> 3, tc = (threadIdx.x & 7) << 2;
  const float4 v = *(const float4*)(W + (size_t)(r0 + tr) * ldW + c0 + tc);
  s[tr * 36 + tc + 0] = f2b(v.x);
  s[tr * 36 + tc + 1] = f2b(v.y);
  s[tr * 36 + tc + 2] = f2b(v.z);
  s[tr * 36 + tc + 3] = f2b(v.w);
  __syncthreads();
  ushort4 o;
  o.x = s[(tc + 0) * 36 + tr];
  o.y = s[(tc + 1) * 36 + tr];
  o.z = s[(tc + 2) * 36 + tr];
  o.w = s[(tc + 3) * 36 + tr];
  *(ushort4*)(Wt + (size_t)(c0 + tr) * R + r0 + tc) = o;
}

// ---------------------------------------------------------------------------
// RMSNorm (one block per row of 2048) -> bf16.
// ---------------------------------------------------------------------------
__global__ __launch_bounds__(256) void rmsnorm(
    const float* __restrict__ X, const float* __restrict__ g,
    unsigned short* __restrict__ ob) {
  const int row = blockIdx.x;
  const float* x = X + (size_t)row * 2048;
  float ss = 0.f;
  for (int i = threadIdx.x; i < 2048; i += 256) { float v = x[i]; ss += v * v; }
  for (int off = 32; off; off >>= 1) ss += __shfl_down(ss, off, 64);
  __shared__ float red[4];
  if ((threadIdx.x & 63) == 0) red[threadIdx.x >> 6] = ss;
  __syncthreads();
  const float tot = red[0] + red[1] + red[2] + red[3];
  const float r = rsqrtf(tot * (1.f / 2048.f) + 1e-5f);
  for (int i = threadIdx.x; i < 2048; i += 256)
    ob[(size_t)row * 2048 + i] = f2b(x[i] * g[i] * r);
}

// ---------------------------------------------------------------------------
// GEMM: acc[M][N] = A[M][K] * Bt[N][K]^T   (bf16 in, fp32 acc)
// 128x128 tile, BK=32, 4 waves, global_load_lds staging.  (unchanged)
// ---------------------------------------------------------------------------
__global__ __launch_bounds__(256, 2) void gemm_bt(
    const unsigned short* __restrict__ A, const unsigned short* __restrict__ Bt,
    float* Cf, unsigned short* Cb,
    const unsigned short* add1b, const float* add2,
    int N, int K, int epi, int Tld) {
  __shared__ unsigned short As[128 * 32];
  __shared__ unsigned short Bs[128 * 32];
  const int tid = threadIdx.x;
  const int wave = tid >> 6, lane = tid & 63;
  const int quad = lane >> 4, l16 = lane & 15;
  const int m0 = blockIdx.y * 128, n0 = blockIdx.x * 128;
  const int wr = (wave >> 1) * 64, wc = (wave & 1) * 64;

  f32x4 acc[4][4] = {};

  for (int k0 = 0; k0 < K; k0 += 32) {
#pragma unroll
    for (int p = 0; p < 2; ++p) {
      const int idx = p * 256 + tid;
      const int row = idx >> 2, q4 = idx & 3;
      const unsigned short* gA = A + (size_t)(m0 + row) * K + k0 + q4 * 8;
      const unsigned short* gB = Bt + (size_t)(n0 + row) * K + k0 + q4 * 8;
      unsigned short* lA = As + (size_t)(p * 256 + wave * 64) * 8;
      unsigned short* lB = Bs + (size_t)(p * 256 + wave * 64) * 8;
      __builtin_amdgcn_global_load_lds((gvoid_t*)gA, (lvoid_t*)lA, 16, 0, 0);
      __builtin_amdgcn_global_load_lds((gvoid_t*)gB, (lvoid_t*)lB, 16, 0, 0);
    }
    __syncthreads();

    short8 af[4], bf[4];
#pragma unroll
    for (int i = 0; i < 4; ++i)
      af[i] = *(const short8*)(As + (wr + i * 16 + l16) * 32 + quad * 8);
#pragma unroll
    for (int j = 0; j < 4; ++j)
      bf[j] = *(const short8*)(Bs + (wc + j * 16 + l16) * 32 + quad * 8);
#pragma unroll
    for (int i = 0; i < 4; ++i)
#pragma unroll
      for (int j = 0; j < 4; ++j)
        acc[i][j] = __builtin_amdgcn_mfma_f32_16x16x32_bf16(af[i], bf[j],
                                                            acc[i][j], 0, 0, 0);
    __syncthreads();
  }

  if (epi == 6) {   // transposed V store
#pragma unroll
    for (int i = 0; i < 4; ++i)
#pragma unroll
      for (int j = 0; j < 4; ++j) {
        const int row = m0 + wr + i * 16 + quad * 4;
        const int col = n0 + wc + j * 16 + l16;
        ushort4 o;
        o.x = f2b(acc[i][j][0]); o.y = f2b(acc[i][j][1]);
        o.z = f2b(acc[i][j][2]); o.w = f2b(acc[i][j][3]);
        *(ushort4*)(Cb + (size_t)col * Tld + row) = o;
      }
    return;
  }

#pragma unroll
  for (int i = 0; i < 4; ++i)
#pragma unroll
    for (int j = 0; j < 4; ++j) {
      const int rowb = m0 + wr + i * 16 + quad * 4;
      const int col = n0 + wc + j * 16 + l16;
      float invf = 0.f, sgn = 0.f;
      if (epi == 5) {
        const int ip = (col & 63) >> 1;
        invf = __expf(-(float)ip * 0.28782313662f); // 10000^(-ip/32)
        sgn = (col & 1) ? 1.f : -1.f;
      }
#pragma unroll
      for (int r = 0; r < 4; ++r) {
        const size_t idx = (size_t)(rowb + r) * N + col;
        const float v = acc[i][j][r];
        const float p = __shfl_xor(v, 1, 64);
        if (epi == 1) {
          Cf[idx] = v + b2f(add1b[idx]);
        } else if (epi == 2) {
          Cf[idx] = v + b2f(add1b[idx]) + add2[idx];
        } else if (epi == 3) {
          const float gt = b2f(add1b[idx]);
          Cb[idx] = f2b(gt / (1.f + __expf(-gt)) * v);
        } else if (epi == 4) {
          Cb[idx] = f2b(v);
        } else {  // 5: rope
          float sn, cs;
          __sincosf((float)(rowb + r) * invf, &sn, &cs);
          Cb[idx] = f2b(v * cs + sgn * p * sn);
        }
      }
    }
}

// ---------------------------------------------------------------------------
// Flash attention, flash-decoding style.  Block = 4 waves, one block per
// (head, 16-row Q-tile).  Wave w handles 128-key chunks jt = w, w+4, ...
// with private online-softmax state; LDS merge at the end.
// Qb [T][2048] roped; Kb [T][512] roped; Vt [512][T].  Y bf16 [T][2048].
// Mask = -3e38 with running max floored at -1e30 so fully-masked chunks
// contribute exp(<-1e38) = 0 (avoids the exp(0)=1 trap).
// ---------------------------------------------------------------------------
#define PSTR 136   // P row stride (bf16 elems); 16B-aligned (136*2=272)
__global__ __launch_bounds__(256) void flash_attn(
    const unsigned short* __restrict__ Qb, const unsigned short* __restrict__ Kb,
    const unsigned short* __restrict__ Vt, unsigned short* __restrict__ Y,
    int T) {
  __shared__ unsigned short P[4][16 * PSTR];  // per-wave P (16 q x 128 k)
  __shared__ float OW[4][4][16][16];          // [wave][dchunk][row][l16]
  __shared__ float mW[4][16], lW[4][16];

  const int tid = threadIdx.x;
  const int wave = tid >> 6, lane = tid & 63;
  const int quad = lane >> 4, l16 = lane & 15;
  const int h = blockIdx.y, qt = blockIdx.x;
  const int kvh = h >> 2;
  const int qbase = qt * 16;

  short8 aQ[2];
#pragma unroll
  for (int c = 0; c < 2; ++c)
    aQ[c] = *(const short8*)(Qb + (size_t)(qbase + l16) * 2048 + h * 64 +
                             c * 32 + quad * 8);

  float m_i[4], l_i[4];
  f32x4 Oacc[4] = {};
#pragma unroll
  for (int r = 0; r < 4; ++r) { m_i[r] = -1e30f; l_i[r] = 0.f; }

  unsigned short* Pw = &P[wave][0];
  const int nchunk = (qbase + 16 + 127) >> 7;   // keys 0 .. qbase+15

  for (int jt = wave; jt < nchunk; jt += 4) {
    const int k0 = jt << 7;
    // ---- QK^T: 8 x 16-key subtiles, K=64 (2 MFMAs each, independent).
    f32x4 S[8];
#pragma unroll
    for (int s = 0; s < 8; ++s) {
      const size_t kr = (size_t)(k0 + s * 16 + l16) * 512 + kvh * 64;
      const short8 b0 = *(const short8*)(Kb + kr + quad * 8);
      const short8 b1 = *(const short8*)(Kb + kr + 32 + quad * 8);
      f32x4 z = {};
      z = __builtin_amdgcn_mfma_f32_16x16x32_bf16(aQ[0], b0, z, 0, 0, 0);
      z = __builtin_amdgcn_mfma_f32_16x16x32_bf16(aQ[1], b1, z, 0, 0, 0);
      S[s] = z;
    }
    // ---- scale + causal mask + row max (regs first, then 4 shfl steps).
    float tmax[4];
#pragma unroll
    for (int r = 0; r < 4; ++r) {
      const int qrow = qbase + quad * 4 + r;
      float mx = -3e38f;
#pragma unroll
      for (int s = 0; s < 8; ++s) {
        const int key = k0 + s * 16 + l16;
        float v = S[s][r] * 0.125f;
        if (key > qrow) v = -3e38f;
        S[s][r] = v;
        mx = fmaxf(mx, v);
      }
      tmax[r] = mx;
    }
#pragma unroll
    for (int off = 1; off < 16; off <<= 1)
#pragma unroll
      for (int r = 0; r < 4; ++r)
        tmax[r] = fmaxf(tmax[r], __shfl_xor(tmax[r], off, 64));

    // ---- online-softmax update (m floored at -1e30 via init).
    float alpha[4], rsum[4];
#pragma unroll
    for (int r = 0; r < 4; ++r) {
      const float mn = fmaxf(m_i[r], tmax[r]);
      alpha[r] = __expf(m_i[r] - mn);
      m_i[r] = mn;
      float acc = 0.f;
#pragma unroll
      for (int s = 0; s < 8; ++s) {
        const float p = __expf(S[s][r] - mn);
        S[s][r] = p;
        acc += p;
      }
      rsum[r] = acc;
    }
#pragma unroll
    for (int off = 1; off < 16; off <<= 1)
#pragma unroll
      for (int r = 0; r < 4; ++r)
        rsum[r] += __shfl_xor(rsum[r], off, 64);
#pragma unroll
    for (int r = 0; r < 4; ++r) l_i[r] = l_i[r] * alpha[r] + rsum[r];

    // ---- P: C-layout -> per-wave LDS -> A-frags (no block barrier).
#pragma unroll
    for (int s = 0; s < 8; ++s)
#pragma unroll
      for (int r = 0; r < 4; ++r)
        Pw[(quad * 4 + r) * PSTR + s * 16 + l16] = f2b(S[s][r]);
    __threadfence_block();   // lgkmcnt drain: writes visible to own wave
    short8 aP[4];
#pragma unroll
    for (int kc = 0; kc < 4; ++kc)
      aP[kc] = *(const short8*)(Pw + l16 * PSTR + kc * 32 + quad * 8);

    // ---- rescale O, then PV over 4 key-chunks x 4 d-chunks.
#pragma unroll
    for (int c = 0; c < 4; ++c)
#pragma unroll
      for (int r = 0; r < 4; ++r) Oacc[c][r] *= alpha[r];
#pragma unroll
    for (int c = 0; c < 4; ++c) {
      const size_t vr = (size_t)(kvh * 64 + c * 16 + l16) * T + k0;
#pragma unroll
      for (int kc = 0; kc < 4; ++kc) {
        const short8 bV = *(const short8*)(Vt + vr + kc * 32 + quad * 8);
        Oacc[c] = __builtin_amdgcn_mfma_f32_16x16x32_bf16(aP[kc], bV,
                                                          Oacc[c], 0, 0, 0);
      }
    }
  }

  // ---- merge the 4 per-wave partials (uniform barrier).
  if (l16 == 0)
#pragma unroll
    for (int r = 0; r < 4; ++r) {
      mW[wave][quad * 4 + r] = m_i[r];
      lW[wave][quad * 4 + r] = l_i[r];
    }
#pragma unroll
  for (int c = 0; c < 4; ++c)
#pragma unroll
    for (int r = 0; r < 4; ++r)
      OW[wave][c][quad * 4 + r][l16] = Oacc[c][r];
  __syncthreads();

  const int c = wave;   // this wave merges d-chunk c
#pragma unroll
  for (int r = 0; r < 4; ++r) {
    const int row = quad * 4 + r;
    float M = mW[0][row];
#pragma unroll
    for (int w2 = 1; w2 < 4; ++w2) M = fmaxf(M, mW[w2][row]);
    float num = 0.f, den = 0.f;
#pragma unroll
    for (int w2 = 0; w2 < 4; ++w2) {
      const float sc = __expf(mW[w2][row] - M);
      den += lW[w2][row] * sc;
      num += OW[w2][c][row][l16] * sc;
    }
    Y[(size_t)(qbase + row) * 2048 + h * 64 + c * 16 + l16] = f2b(num / den);
  }
}

// ---------------------------------------------------------------------------
extern "C" void kernel_launch(void* const* d_in, const int* in_sizes, int n_in,
                              void* d_out, int out_size, void* d_ws,
                              size_t ws_size, hipStream_t stream) {
  const float* x  = (const float*)d_in[0];
  const float* g1 = (const float*)d_in[1];
  const float* wq = (const float*)d_in[2];
  const float* wk = (const float*)d_in[3];
  const float* wv = (const float*)d_in[4];
  const float* wo = (const float*)d_in[5];
  const float* g2 = (const float*)d_in[6];
  const float* wg = (const float*)d_in[7];
  const float* wu = (const float*)d_in[8];
  const float* wd = (const float*)d_in[9];
  float* out = (float*)d_out;

  const int T = 2048, Dm = 2048, FF = 8192;
  char* ws = (char*)d_ws;
  const size_t MB = (size_t)1 << 20;

  unsigned short* wq_t = (unsigned short*)(ws + 0 * MB);    // 8 MB
  unsigned short* wk_t = (unsigned short*)(ws + 8 * MB);    // 2 MB
  unsigned short* wv_t = (unsigned short*)(ws + 10 * MB);   // 2 MB
  unsigned short* wo_t = (unsigned short*)(ws + 12 * MB);   // 8 MB
  unsigned short* wg_t = (unsigned short*)(ws + 20 * MB);   // 32 MB
  unsigned short* wu_t = (unsigned short*)(ws + 52 * MB);   // 32 MB
  unsigned short* h1_b = (unsigned short*)(ws + 84 * MB);   // 8 MB
  unsigned short* h2_b = (unsigned short*)(ws + 92 * MB);   // 8 MB
  float*          x2_f = (float*)(ws + 100 * MB);           // 16 MB (dies early)
  unsigned short* gate = (unsigned short*)(ws + 100 * MB);  // 32 MB (in-place)
  unsigned short* q_b  = (unsigned short*)(ws + 132 * MB);  // 8 MB
  unsigned short* k_b  = (unsigned short*)(ws + 140 * MB);  // 2 MB
  unsigned short* vt_b = (unsigned short*)(ws + 142 * MB);  // 2 MB
  unsigned short* y_b  = (unsigned short*)(ws + 144 * MB);  // 8 MB
  unsigned short* wd_t = (unsigned short*)(ws + 132 * MB);  // 32 MB (after attn)

  // 1. Weight cast+transpose (wd deferred until attn scratch is dead).
  transpose_cast<<<dim3(64, 64), 256, 0, stream>>>(wq, wq_t, Dm, Dm);
  transpose_cast<<<dim3(16, 64), 256, 0, stream>>>(wk, wk_t, Dm, 512);
  transpose_cast<<<dim3(16, 64), 256, 0, stream>>>(wv, wv_t, Dm, 512);
  transpose_cast<<<dim3(64, 64), 256, 0, stream>>>(wo, wo_t, Dm, Dm);
  transpose_cast<<<dim3(256, 64), 256, 0, stream>>>(wg, wg_t, Dm, FF);
  transpose_cast<<<dim3(256, 64), 256, 0, stream>>>(wu, wu_t, Dm, FF);

  // 2. h1 = rms(x0)
  rmsnorm<<<T, 256, 0, stream>>>(x, g1, h1_b);

  // 3. Q/K/V projections; rope fused (epi 5), V transposed store (epi 6).
  gemm_bt<<<dim3(16, 16), 256, 0, stream>>>(h1_b, wq_t, nullptr, q_b, nullptr,
                                            nullptr, Dm, Dm, 5, 0);
  gemm_bt<<<dim3(4, 16), 256, 0, stream>>>(h1_b, wk_t, nullptr, k_b, nullptr,
                                           nullptr, 512, Dm, 5, 0);
  gemm_bt<<<dim3(4, 16), 256, 0, stream>>>(h1_b, wv_t, nullptr, vt_b, nullptr,
                                           nullptr, 512, Dm, 6, T);

  // 4. Attention (4 waves/block, key-split).
  flash_attn<<<dim3(T / 16, 32), 256, 0, stream>>>(q_b, k_b, vt_b, y_b, T);

  // 5. x2 = h1 + y @ wo  (epi 1).
  gemm_bt<<<dim3(16, 16), 256, 0, stream>>>(y_b, wo_t, x2_f, nullptr, h1_b,
                                            nullptr, Dm, Dm, 1, 0);

  // 6. wd transpose into the now-dead attention scratch.
  transpose_cast<<<dim3(64, 256), 256, 0, stream>>>(wd, wd_t, FF, Dm);

  // 7. h2 = rms(x2)
  rmsnorm<<<T, 256, 0, stream>>>(x2_f, g2, h2_b);

  // 8. MLP: gate (epi 4), then up fused with silu in-place (epi 3).
  gemm_bt<<<dim3(64, 16), 256, 0, stream>>>(h2_b, wg_t, nullptr, gate, nullptr,
                                            nullptr, FF, Dm, 4, 0);
  gemm_bt<<<dim3(64, 16), 256, 0, stream>>>(h2_b, wu_t, nullptr, gate, gate,
                                            nullptr, FF, Dm, 3, 0);

  // 9. out = act @ wd + h2 + x0  (epi 2).
  gemm_bt<<<dim3(16, 16), 256, 0, stream>>>(gate, wd_t, out, nullptr, h2_b, x,
                                            Dm, FF, 2, 0);
}

// Round 4
// 902.261 us; speedup vs baseline: 1.1688x; 1.0965x over previous
//
#include <hip/hip_runtime.h>
#include <cstdint>
#include <cstddef>

// ---------------------------------------------------------------------------
// Llama decoder layer, MI355X.  B=1, T=2048, D=2048, FF=8192, NH=32, NKV=8,
// HD=64.  bf16 MFMA (16x16x32), fp32 accumulate.
// out = h2 + mlp(h2) + x0, where h2 = rms(h1 + attn(h1)), h1 = rms(x0).
//
// Round 4: (a) flash_attn LDS 34->17 KB (per-wave slice reuse) + LJF block
// order — was occupancy-capped at 4 blocks/CU; (b) QKV projections merged
// into one N=3072 GEMM (wq_t/wk_t/wv_t contiguous), epilogue region branch
// is block-uniform (boundaries at multiples of 128).
// ---------------------------------------------------------------------------

typedef __attribute__((ext_vector_type(8))) short short8;   // 8 x bf16
typedef __attribute__((ext_vector_type(4))) float f32x4;

typedef __attribute__((address_space(1))) const void gvoid_t;  // global
typedef __attribute__((address_space(3))) void lvoid_t;        // LDS

__device__ inline unsigned short f2b(float f) {   // fp32 -> bf16 (RNE)
  unsigned int u = __float_as_uint(f);
  u += 0x7fffu + ((u >> 16) & 1u);
  return (unsigned short)(u >> 16);
}
__device__ inline float b2f(unsigned short s) {
  return __uint_as_float((unsigned int)s << 16);
}

// ---------------------------------------------------------------------------
// Cast + transpose:  W fp32 [R][ldW]  ->  Wt bf16 [ldW-cols][R]
// ---------------------------------------------------------------------------
__global__ __launch_bounds__(256) void transpose_cast(
    const float* __restrict__ W, unsigned short* __restrict__ Wt,
    int R, int ldW) {
  __shared__ unsigned short s[32 * 36];
  const int r0 = blockIdx.y * 32, c0 = blockIdx.x * 32;
  const int tr = threadIdx.x >> 3, tc = (threadIdx.x & 7) << 2;
  const float4 v = *(const float4*)(W + (size_t)(r0 + tr) * ldW + c0 + tc);
  s[tr * 36 + tc + 0] = f2b(v.x);
  s[tr * 36 + tc + 1] = f2b(v.y);
  s[tr * 36 + tc + 2] = f2b(v.z);
  s[tr * 36 + tc + 3] = f2b(v.w);
  __syncthreads();
  ushort4 o;
  o.x = s[(tc + 0) * 36 + tr];
  o.y = s[(tc + 1) * 36 + tr];
  o.z = s[(tc + 2) * 36 + tr];
  o.w = s[(tc + 3) * 36 + tr];
  *(ushort4*)(Wt + (size_t)(c0 + tr) * R + r0 + tc) = o;
}

// ---------------------------------------------------------------------------
// RMSNorm (one block per row of 2048) -> bf16.
// ---------------------------------------------------------------------------
__global__ __launch_bounds__(256) void rmsnorm(
    const float* __restrict__ X, const float* __restrict__ g,
    unsigned short* __restrict__ ob) {
  const int row = blockIdx.x;
  const float* x = X + (size_t)row * 2048;
  float ss = 0.f;
  for (int i = threadIdx.x; i < 2048; i += 256) { float v = x[i]; ss += v * v; }
  for (int off = 32; off; off >>= 1) ss += __shfl_down(ss, off, 64);
  __shared__ float red[4];
  if ((threadIdx.x & 63) == 0) red[threadIdx.x >> 6] = ss;
  __syncthreads();
  const float tot = red[0] + red[1] + red[2] + red[3];
  const float r = rsqrtf(tot * (1.f / 2048.f) + 1e-5f);
  for (int i = threadIdx.x; i < 2048; i += 256)
    ob[(size_t)row * 2048 + i] = f2b(x[i] * g[i] * r);
}

// ---------------------------------------------------------------------------
// GEMM: acc[M][N] = A[M][K] * Bt[N][K]^T   (bf16 in, fp32 acc)
// 128x128 tile, BK=32, 4 waves, global_load_lds staging.
// Epilogues:
//   1: Cf = acc + b2f(add1b)                       (wo + residual h1)
//   2: Cf = acc + b2f(add1b) + add2                (down + h2 + x0)
//   3: Cb = f2b( silu(b2f(add1b)) * acc )          (up; in-place over gate)
//   4: Cb = f2b(acc)                               (gate)
//   7: fused QKV, block-uniform by col region:
//        col <  2048: rope -> Cb  [row*2048+col]         (q)
//        col <  2560: rope -> Cb2 [row*512+col-2048]     (k)
//        col >= 2560: Cb3[(col-2560)*Tld + row] (transposed V, ushort4)
// ---------------------------------------------------------------------------
__global__ __launch_bounds__(256, 2) void gemm_bt(
    const unsigned short* __restrict__ A, const unsigned short* __restrict__ Bt,
    float* Cf, unsigned short* Cb,
    const unsigned short* add1b, const float* add2,
    int N, int K, int epi, int Tld,
    unsigned short* Cb2, unsigned short* Cb3) {
  __shared__ unsigned short As[128 * 32];
  __shared__ unsigned short Bs[128 * 32];
  const int tid = threadIdx.x;
  const int wave = tid >> 6, lane = tid & 63;
  const int quad = lane >> 4, l16 = lane & 15;
  const int m0 = blockIdx.y * 128, n0 = blockIdx.x * 128;
  const int wr = (wave >> 1) * 64, wc = (wave & 1) * 64;

  f32x4 acc[4][4] = {};

  for (int k0 = 0; k0 < K; k0 += 32) {
#pragma unroll
    for (int p = 0; p < 2; ++p) {
      const int idx = p * 256 + tid;
      const int row = idx >> 2, q4 = idx & 3;
      const unsigned short* gA = A + (size_t)(m0 + row) * K + k0 + q4 * 8;
      const unsigned short* gB = Bt + (size_t)(n0 + row) * K + k0 + q4 * 8;
      unsigned short* lA = As + (size_t)(p * 256 + wave * 64) * 8;
      unsigned short* lB = Bs + (size_t)(p * 256 + wave * 64) * 8;
      __builtin_amdgcn_global_load_lds((gvoid_t*)gA, (lvoid_t*)lA, 16, 0, 0);
      __builtin_amdgcn_global_load_lds((gvoid_t*)gB, (lvoid_t*)lB, 16, 0, 0);
    }
    __syncthreads();

    short8 af[4], bf[4];
#pragma unroll
    for (int i = 0; i < 4; ++i)
      af[i] = *(const short8*)(As + (wr + i * 16 + l16) * 32 + quad * 8);
#pragma unroll
    for (int j = 0; j < 4; ++j)
      bf[j] = *(const short8*)(Bs + (wc + j * 16 + l16) * 32 + quad * 8);
#pragma unroll
    for (int i = 0; i < 4; ++i)
#pragma unroll
      for (int j = 0; j < 4; ++j)
        acc[i][j] = __builtin_amdgcn_mfma_f32_16x16x32_bf16(af[i], bf[j],
                                                            acc[i][j], 0, 0, 0);
    __syncthreads();
  }

  // C/D layout: col = lane&15, row = quad*4 + reg.
  if (epi == 7 && n0 >= 2560) {   // transposed V store (block-uniform)
#pragma unroll
    for (int i = 0; i < 4; ++i)
#pragma unroll
      for (int j = 0; j < 4; ++j) {
        const int row = m0 + wr + i * 16 + quad * 4;
        const int col = n0 + wc + j * 16 + l16 - 2560;
        ushort4 o;
        o.x = f2b(acc[i][j][0]); o.y = f2b(acc[i][j][1]);
        o.z = f2b(acc[i][j][2]); o.w = f2b(acc[i][j][3]);
        *(ushort4*)(Cb3 + (size_t)col * Tld + row) = o;
      }
    return;
  }

#pragma unroll
  for (int i = 0; i < 4; ++i)
#pragma unroll
    for (int j = 0; j < 4; ++j) {
      const int rowb = m0 + wr + i * 16 + quad * 4;
      const int col = n0 + wc + j * 16 + l16;
      float invf = 0.f, sgn = 0.f;
      if (epi == 7) {
        const int ip = (col & 63) >> 1;
        invf = __expf(-(float)ip * 0.28782313662f); // 10000^(-ip/32)
        sgn = (col & 1) ? 1.f : -1.f;
      }
#pragma unroll
      for (int r = 0; r < 4; ++r) {
        const size_t idx = (size_t)(rowb + r) * N + col;
        const float v = acc[i][j][r];
        const float p = __shfl_xor(v, 1, 64);
        if (epi == 1) {
          Cf[idx] = v + b2f(add1b[idx]);
        } else if (epi == 2) {
          Cf[idx] = v + b2f(add1b[idx]) + add2[idx];
        } else if (epi == 3) {
          const float gt = b2f(add1b[idx]);
          Cb[idx] = f2b(gt / (1.f + __expf(-gt)) * v);
        } else if (epi == 4) {
          Cb[idx] = f2b(v);
        } else {  // 7: rope -> q or k (block-uniform region)
          float sn, cs;
          __sincosf((float)(rowb + r) * invf, &sn, &cs);
          const unsigned short o = f2b(v * cs + sgn * p * sn);
          if (col < 2048)
            Cb[(size_t)(rowb + r) * 2048 + col] = o;
          else
            Cb2[(size_t)(rowb + r) * 512 + col - 2048] = o;
        }
      }
    }
}

// ---------------------------------------------------------------------------
// Flash attention, flash-decoding style.  Block = 4 waves, one block per
// (head, 16-row Q-tile); wave w does 128-key chunks jt = w, w+4, ...
// LDS: per-wave 4352 B slice — P buffer during the loop, then O/m/l merge
// partials (4224 B) after it (same wave, no cross-wave aliasing until the
// single uniform barrier).  LJF: qt reversed so 16-chunk blocks go first.
// ---------------------------------------------------------------------------
#define PSTR 136   // P row stride (bf16); 136*2=272 bytes, 16B-aligned
__global__ __launch_bounds__(256) void flash_attn(
    const unsigned short* __restrict__ Qb, const unsigned short* __restrict__ Kb,
    const unsigned short* __restrict__ Vt, unsigned short* __restrict__ Y,
    int T) {
  __shared__ char shmem[4 * 4352];   // 17408 B total

  const int tid = threadIdx.x;
  const int wave = tid >> 6, lane = tid & 63;
  const int quad = lane >> 4, l16 = lane & 15;
  const int h = blockIdx.y;
  const int qt = gridDim.x - 1 - blockIdx.x;   // longest-job-first
  const int kvh = h >> 2;
  const int qbase = qt * 16;

  short8 aQ[2];
#pragma unroll
  for (int c = 0; c < 2; ++c)
    aQ[c] = *(const short8*)(Qb + (size_t)(qbase + l16) * 2048 + h * 64 +
                             c * 32 + quad * 8);

  float m_i[4], l_i[4];
  f32x4 Oacc[4] = {};
#pragma unroll
  for (int r = 0; r < 4; ++r) { m_i[r] = -1e30f; l_i[r] = 0.f; }

  unsigned short* Pw = (unsigned short*)(shmem + wave * 4352);
  const int nchunk = (qbase + 16 + 127) >> 7;   // keys 0 .. qbase+15

  for (int jt = wave; jt < nchunk; jt += 4) {
    const int k0 = jt << 7;
    // ---- QK^T: 8 x 16-key subtiles, K=64.
    f32x4 S[8];
#pragma unroll
    for (int s = 0; s < 8; ++s) {
      const size_t kr = (size_t)(k0 + s * 16 + l16) * 512 + kvh * 64;
      const short8 b0 = *(const short8*)(Kb + kr + quad * 8);
      const short8 b1 = *(const short8*)(Kb + kr + 32 + quad * 8);
      f32x4 z = {};
      z = __builtin_amdgcn_mfma_f32_16x16x32_bf16(aQ[0], b0, z, 0, 0, 0);
      z = __builtin_amdgcn_mfma_f32_16x16x32_bf16(aQ[1], b1, z, 0, 0, 0);
      S[s] = z;
    }
    // ---- scale + causal mask + row max.
    float tmax[4];
#pragma unroll
    for (int r = 0; r < 4; ++r) {
      const int qrow = qbase + quad * 4 + r;
      float mx = -3e38f;
#pragma unroll
      for (int s = 0; s < 8; ++s) {
        const int key = k0 + s * 16 + l16;
        float v = S[s][r] * 0.125f;
        if (key > qrow) v = -3e38f;
        S[s][r] = v;
        mx = fmaxf(mx, v);
      }
      tmax[r] = mx;
    }
#pragma unroll
    for (int off = 1; off < 16; off <<= 1)
#pragma unroll
      for (int r = 0; r < 4; ++r)
        tmax[r] = fmaxf(tmax[r], __shfl_xor(tmax[r], off, 64));

    // ---- online-softmax update (m floored at -1e30 via init).
    float alpha[4], rsum[4];
#pragma unroll
    for (int r = 0; r < 4; ++r) {
      const float mn = fmaxf(m_i[r], tmax[r]);
      alpha[r] = __expf(m_i[r] - mn);
      m_i[r] = mn;
      float acc = 0.f;
#pragma unroll
      for (int s = 0; s < 8; ++s) {
        const float p = __expf(S[s][r] - mn);
        S[s][r] = p;
        acc += p;
      }
      rsum[r] = acc;
    }
#pragma unroll
    for (int off = 1; off < 16; off <<= 1)
#pragma unroll
      for (int r = 0; r < 4; ++r)
        rsum[r] += __shfl_xor(rsum[r], off, 64);
#pragma unroll
    for (int r = 0; r < 4; ++r) l_i[r] = l_i[r] * alpha[r] + rsum[r];

    // ---- P: C-layout -> per-wave LDS slice -> A-frags.
#pragma unroll
    for (int s = 0; s < 8; ++s)
#pragma unroll
      for (int r = 0; r < 4; ++r)
        Pw[(quad * 4 + r) * PSTR + s * 16 + l16] = f2b(S[s][r]);
    __threadfence_block();
    short8 aP[4];
#pragma unroll
    for (int kc = 0; kc < 4; ++kc)
      aP[kc] = *(const short8*)(Pw + l16 * PSTR + kc * 32 + quad * 8);

    // ---- rescale O, then PV.
#pragma unroll
    for (int c = 0; c < 4; ++c)
#pragma unroll
      for (int r = 0; r < 4; ++r) Oacc[c][r] *= alpha[r];
#pragma unroll
    for (int c = 0; c < 4; ++c) {
      const size_t vr = (size_t)(kvh * 64 + c * 16 + l16) * T + k0;
#pragma unroll
      for (int kc = 0; kc < 4; ++kc) {
        const short8 bV = *(const short8*)(Vt + vr + kc * 32 + quad * 8);
        Oacc[c] = __builtin_amdgcn_mfma_f32_16x16x32_bf16(aP[kc], bV,
                                                          Oacc[c], 0, 0, 0);
      }
    }
  }

  // ---- write own partials into own slice (P is dead for this wave).
  float* OWw = (float*)(shmem + wave * 4352);          // [c][row][l16]
  float* mw  = (float*)(shmem + wave * 4352 + 4096);
  float* lw  = (float*)(shmem + wave * 4352 + 4160);
#pragma unroll
  for (int c = 0; c < 4; ++c)
#pragma unroll
    for (int r = 0; r < 4; ++r)
      OWw[c * 256 + (quad * 4 + r) * 16 + l16] = Oacc[c][r];
  if (l16 == 0)
#pragma unroll
    for (int r = 0; r < 4; ++r) {
      mw[quad * 4 + r] = m_i[r];
      lw[quad * 4 + r] = l_i[r];
    }
  __syncthreads();

  // ---- merge: this wave handles d-chunk c = wave.
  const int c = wave;
#pragma unroll
  for (int r = 0; r < 4; ++r) {
    const int row = quad * 4 + r;
    float M = -3e38f;
#pragma unroll
    for (int w2 = 0; w2 < 4; ++w2)
      M = fmaxf(M, ((const float*)(shmem + w2 * 4352 + 4096))[row]);
    float num = 0.f, den = 0.f;
#pragma unroll
    for (int w2 = 0; w2 < 4; ++w2) {
      const float mv = ((const float*)(shmem + w2 * 4352 + 4096))[row];
      const float lv = ((const float*)(shmem + w2 * 4352 + 4160))[row];
      const float sc = __expf(mv - M);
      den += lv * sc;
      num += ((const float*)(shmem + w2 * 4352))[c * 256 + row * 16 + l16] * sc;
    }
    Y[(size_t)(qbase + row) * 2048 + h * 64 + c * 16 + l16] = f2b(num / den);
  }
}

// ---------------------------------------------------------------------------
extern "C" void kernel_launch(void* const* d_in, const int* in_sizes, int n_in,
                              void* d_out, int out_size, void* d_ws,
                              size_t ws_size, hipStream_t stream) {
  const float* x  = (const float*)d_in[0];
  const float* g1 = (const float*)d_in[1];
  const float* wq = (const float*)d_in[2];
  const float* wk = (const float*)d_in[3];
  const float* wv = (const float*)d_in[4];
  const float* wo = (const float*)d_in[5];
  const float* g2 = (const float*)d_in[6];
  const float* wg = (const float*)d_in[7];
  const float* wu = (const float*)d_in[8];
  const float* wd = (const float*)d_in[9];
  float* out = (float*)d_out;

  const int T = 2048, Dm = 2048, FF = 8192;
  char* ws = (char*)d_ws;
  const size_t MB = (size_t)1 << 20;

  unsigned short* wq_t = (unsigned short*)(ws + 0 * MB);    // 8 MB  } contig
  unsigned short* wk_t = (unsigned short*)(ws + 8 * MB);    // 2 MB  } rows
  unsigned short* wv_t = (unsigned short*)(ws + 10 * MB);   // 2 MB  } 0..3071
  unsigned short* wo_t = (unsigned short*)(ws + 12 * MB);   // 8 MB
  unsigned short* wg_t = (unsigned short*)(ws + 20 * MB);   // 32 MB
  unsigned short* wu_t = (unsigned short*)(ws + 52 * MB);   // 32 MB
  unsigned short* h1_b = (unsigned short*)(ws + 84 * MB);   // 8 MB
  unsigned short* h2_b = (unsigned short*)(ws + 92 * MB);   // 8 MB
  float*          x2_f = (float*)(ws + 100 * MB);           // 16 MB (dies early)
  unsigned short* gate = (unsigned short*)(ws + 100 * MB);  // 32 MB (in-place)
  unsigned short* q_b  = (unsigned short*)(ws + 132 * MB);  // 8 MB
  unsigned short* k_b  = (unsigned short*)(ws + 140 * MB);  // 2 MB
  unsigned short* vt_b = (unsigned short*)(ws + 142 * MB);  // 2 MB
  unsigned short* y_b  = (unsigned short*)(ws + 144 * MB);  // 8 MB
  unsigned short* wd_t = (unsigned short*)(ws + 132 * MB);  // 32 MB (after attn)

  // 1. Weight cast+transpose (wd deferred until attn scratch is dead).
  transpose_cast<<<dim3(64, 64), 256, 0, stream>>>(wq, wq_t, Dm, Dm);
  transpose_cast<<<dim3(16, 64), 256, 0, stream>>>(wk, wk_t, Dm, 512);
  transpose_cast<<<dim3(16, 64), 256, 0, stream>>>(wv, wv_t, Dm, 512);
  transpose_cast<<<dim3(64, 64), 256, 0, stream>>>(wo, wo_t, Dm, Dm);
  transpose_cast<<<dim3(256, 64), 256, 0, stream>>>(wg, wg_t, Dm, FF);
  transpose_cast<<<dim3(256, 64), 256, 0, stream>>>(wu, wu_t, Dm, FF);

  // 2. h1 = rms(x0)
  rmsnorm<<<T, 256, 0, stream>>>(x, g1, h1_b);

  // 3. Fused QKV projection (N=3072): rope q -> q_b, rope k -> k_b,
  //    transposed v -> vt_b.
  gemm_bt<<<dim3(24, 16), 256, 0, stream>>>(h1_b, wq_t, nullptr, q_b, nullptr,
                                            nullptr, 3072, Dm, 7, T, k_b, vt_b);

  // 4. Attention (4 waves/block, key-split, LJF).
  flash_attn<<<dim3(T / 16, 32), 256, 0, stream>>>(q_b, k_b, vt_b, y_b, T);

  // 5. x2 = h1 + y @ wo  (epi 1).
  gemm_bt<<<dim3(16, 16), 256, 0, stream>>>(y_b, wo_t, x2_f, nullptr, h1_b,
                                            nullptr, Dm, Dm, 1, 0, nullptr,
                                            nullptr);

  // 6. wd transpose into the now-dead attention scratch.
  transpose_cast<<<dim3(64, 256), 256, 0, stream>>>(wd, wd_t, FF, Dm);

  // 7. h2 = rms(x2)
  rmsnorm<<<T, 256, 0, stream>>>(x2_f, g2, h2_b);

  // 8. MLP: gate (epi 4), then up fused with silu in-place (epi 3).
  gemm_bt<<<dim3(64, 16), 256, 0, stream>>>(h2_b, wg_t, nullptr, gate, nullptr,
                                            nullptr, FF, Dm, 4, 0, nullptr,
                                            nullptr);
  gemm_bt<<<dim3(64, 16), 256, 0, stream>>>(h2_b, wu_t, nullptr, gate, gate,
                                            nullptr, FF, Dm, 3, 0, nullptr,
                                            nullptr);

  // 9. out = act @ wd + h2 + x0  (epi 2).
  gemm_bt<<<dim3(16, 16), 256, 0, stream>>>(gate, wd_t, out, nullptr, h2_b, x,
                                            Dm, FF, 2, 0, nullptr, nullptr);
}

// Round 5
// 817.638 us; speedup vs baseline: 1.2897x; 1.1035x over previous
//
#include <hip/hip_runtime.h>
#include <cstdint>
#include <cstddef>

// ---------------------------------------------------------------------------
// Llama decoder layer, MI355X.  B=1, T=2048, D=2048, FF=8192, NH=32, NKV=8,
// HD=64.  bf16 MFMA (16x16x32), fp32 accumulate.
// out = h2 + mlp(h2) + x0, where h2 = rms(h1 + attn(h1)), h1 = rms(x0).
//
// Round 5: (a) GEMM BK 32->64 (32 MFMA/wave per barrier, AITER's ratio) with
// XOR k-chunk swizzle to keep 32-bank LDS coverage (global_load_lds forces
// contiguous LDS, so the permute happens on the global address side);
// (b) down-proj split-K x4 (was 1 block/CU) via out=h2+x0 pre-fill +
// fp32 atomicAdd epilogue.
// ---------------------------------------------------------------------------

typedef __attribute__((ext_vector_type(8))) short short8;   // 8 x bf16
typedef __attribute__((ext_vector_type(4))) float f32x4;

typedef __attribute__((address_space(1))) const void gvoid_t;  // global
typedef __attribute__((address_space(3))) void lvoid_t;        // LDS

__device__ inline unsigned short f2b(float f) {   // fp32 -> bf16 (RNE)
  unsigned int u = __float_as_uint(f);
  u += 0x7fffu + ((u >> 16) & 1u);
  return (unsigned short)(u >> 16);
}
__device__ inline float b2f(unsigned short s) {
  return __uint_as_float((unsigned int)s << 16);
}

// ---------------------------------------------------------------------------
// Cast + transpose:  W fp32 [R][ldW]  ->  Wt bf16 [ldW-cols][R]
// ---------------------------------------------------------------------------
__global__ __launch_bounds__(256) void transpose_cast(
    const float* __restrict__ W, unsigned short* __restrict__ Wt,
    int R, int ldW) {
  __shared__ unsigned short s[32 * 36];
  const int r0 = blockIdx.y * 32, c0 = blockIdx.x * 32;
  const int tr = threadIdx.x >> 3, tc = (threadIdx.x & 7) << 2;
  const float4 v = *(const float4*)(W + (size_t)(r0 + tr) * ldW + c0 + tc);
  s[tr * 36 + tc + 0] = f2b(v.x);
  s[tr * 36 + tc + 1] = f2b(v.y);
  s[tr * 36 + tc + 2] = f2b(v.z);
  s[tr * 36 + tc + 3] = f2b(v.w);
  __syncthreads();
  ushort4 o;
  o.x = s[(tc + 0) * 36 + tr];
  o.y = s[(tc + 1) * 36 + tr];
  o.z = s[(tc + 2) * 36 + tr];
  o.w = s[(tc + 3) * 36 + tr];
  *(ushort4*)(Wt + (size_t)(c0 + tr) * R + r0 + tc) = o;
}

// ---------------------------------------------------------------------------
// RMSNorm (one block per row of 2048) -> bf16.
// ---------------------------------------------------------------------------
__global__ __launch_bounds__(256) void rmsnorm(
    const float* __restrict__ X, const float* __restrict__ g,
    unsigned short* __restrict__ ob) {
  const int row = blockIdx.x;
  const float* x = X + (size_t)row * 2048;
  float ss = 0.f;
  for (int i = threadIdx.x; i < 2048; i += 256) { float v = x[i]; ss += v * v; }
  for (int off = 32; off; off >>= 1) ss += __shfl_down(ss, off, 64);
  __shared__ float red[4];
  if ((threadIdx.x & 63) == 0) red[threadIdx.x >> 6] = ss;
  __syncthreads();
  const float tot = red[0] + red[1] + red[2] + red[3];
  const float r = rsqrtf(tot * (1.f / 2048.f) + 1e-5f);
  for (int i = threadIdx.x; i < 2048; i += 256)
    ob[(size_t)row * 2048 + i] = f2b(x[i] * g[i] * r);
}

// ---------------------------------------------------------------------------
// out = x0 + b2f(h2), vectorized x4.  Pre-fill for the split-K down-proj.
// ---------------------------------------------------------------------------
__global__ __launch_bounds__(256) void add_res(
    const unsigned short* __restrict__ h2, const float* __restrict__ x,
    float* __restrict__ out) {
  const int i = blockIdx.x * 256 + threadIdx.x;
  const ushort4 h = ((const ushort4*)h2)[i];
  const float4 xv = ((const float4*)x)[i];
  float4 o;
  o.x = xv.x + b2f(h.x); o.y = xv.y + b2f(h.y);
  o.z = xv.z + b2f(h.z); o.w = xv.w + b2f(h.w);
  ((float4*)out)[i] = o;
}

// ---------------------------------------------------------------------------
// GEMM: acc[M][N] (+)= A[M][K] * Bt[N][K]^T   (bf16 in, fp32 acc)
// 128x128 tile, BK=64 (32 MFMA/wave per barrier), 4 waves,
// global_load_lds staging with XOR k-chunk swizzle:
//   LDS[row][c] holds global chunk c ^ (row&7)  (8-elem chunks) — keeps all
//   32 banks active on ds_read_b128 despite the forced-contiguous 128B rows.
// K-range per block: [blockIdx.z*Kchunk, +Kchunk)  (split-K when gridDim.z>1).
// Epilogues:
//   1: Cf = acc + b2f(add1b)                       (wo + residual h1)
//   3: Cb = f2b( silu(b2f(add1b)) * acc )          (up; in-place over gate)
//   4: Cb = f2b(acc)                               (gate)
//   7: fused QKV, block-uniform by col region (rope q/k, transposed v)
//   8: atomicAdd(Cf, acc)                          (split-K down-proj)
// ---------------------------------------------------------------------------
__global__ __launch_bounds__(256, 2) void gemm_bt(
    const unsigned short* __restrict__ A, const unsigned short* __restrict__ Bt,
    float* Cf, unsigned short* Cb,
    const unsigned short* add1b, const float* add2,
    int N, int Kfull, int Kchunk, int epi, int Tld,
    unsigned short* Cb2, unsigned short* Cb3) {
  __shared__ unsigned short As[128 * 64];
  __shared__ unsigned short Bs[128 * 64];
  const int tid = threadIdx.x;
  const int wave = tid >> 6, lane = tid & 63;
  const int quad = lane >> 4, l16 = lane & 15;
  const int m0 = blockIdx.y * 128, n0 = blockIdx.x * 128;
  const int wr = (wave >> 1) * 64, wc = (wave & 1) * 64;
  const int Ks = blockIdx.z * Kchunk, Ke = Ks + Kchunk;

  f32x4 acc[4][4] = {};

  for (int k0 = Ks; k0 < Ke; k0 += 64) {
    // Stage A/B 128x64 tiles.  LDS dest forced to idx*16B (wave-uniform base
    // + lane*16); global chunk is XOR-permuted within the row's 128B span.
#pragma unroll
    for (int p = 0; p < 4; ++p) {
      const int idx = p * 256 + tid;
      const int row = idx >> 3;
      const int kc = ((idx & 7) ^ (row & 7)) * 8;
      const unsigned short* gA = A + (size_t)(m0 + row) * Kfull + k0 + kc;
      const unsigned short* gB = Bt + (size_t)(n0 + row) * Kfull + k0 + kc;
      unsigned short* lA = As + (size_t)(p * 256 + wave * 64) * 8;
      unsigned short* lB = Bs + (size_t)(p * 256 + wave * 64) * 8;
      __builtin_amdgcn_global_load_lds((gvoid_t*)gA, (lvoid_t*)lA, 16, 0, 0);
      __builtin_amdgcn_global_load_lds((gvoid_t*)gB, (lvoid_t*)lB, 16, 0, 0);
    }
    __syncthreads();

#pragma unroll
    for (int ks = 0; ks < 2; ++ks) {
      short8 af[4], bf[4];
#pragma unroll
      for (int i = 0; i < 4; ++i) {
        const int row = wr + i * 16 + l16;
        af[i] = *(const short8*)(As + row * 64 +
                                 (((ks << 2) | quad) ^ (row & 7)) * 8);
      }
#pragma unroll
      for (int j = 0; j < 4; ++j) {
        const int row = wc + j * 16 + l16;
        bf[j] = *(const short8*)(Bs + row * 64 +
                                 (((ks << 2) | quad) ^ (row & 7)) * 8);
      }
#pragma unroll
      for (int i = 0; i < 4; ++i)
#pragma unroll
        for (int j = 0; j < 4; ++j)
          acc[i][j] = __builtin_amdgcn_mfma_f32_16x16x32_bf16(
              af[i], bf[j], acc[i][j], 0, 0, 0);
    }
    __syncthreads();
  }

  // C/D layout: col = lane&15, row = quad*4 + reg.
  if (epi == 7 && n0 >= 2560) {   // transposed V store (block-uniform)
#pragma unroll
    for (int i = 0; i < 4; ++i)
#pragma unroll
      for (int j = 0; j < 4; ++j) {
        const int row = m0 + wr + i * 16 + quad * 4;
        const int col = n0 + wc + j * 16 + l16 - 2560;
        ushort4 o;
        o.x = f2b(acc[i][j][0]); o.y = f2b(acc[i][j][1]);
        o.z = f2b(acc[i][j][2]); o.w = f2b(acc[i][j][3]);
        *(ushort4*)(Cb3 + (size_t)col * Tld + row) = o;
      }
    return;
  }

#pragma unroll
  for (int i = 0; i < 4; ++i)
#pragma unroll
    for (int j = 0; j < 4; ++j) {
      const int rowb = m0 + wr + i * 16 + quad * 4;
      const int col = n0 + wc + j * 16 + l16;
      float invf = 0.f, sgn = 0.f;
      if (epi == 7) {
        const int ip = (col & 63) >> 1;
        invf = __expf(-(float)ip * 0.28782313662f); // 10000^(-ip/32)
        sgn = (col & 1) ? 1.f : -1.f;
      }
#pragma unroll
      for (int r = 0; r < 4; ++r) {
        const size_t idx = (size_t)(rowb + r) * N + col;
        const float v = acc[i][j][r];
        const float p = __shfl_xor(v, 1, 64);
        if (epi == 1) {
          Cf[idx] = v + b2f(add1b[idx]);
        } else if (epi == 3) {
          const float gt = b2f(add1b[idx]);
          Cb[idx] = f2b(gt / (1.f + __expf(-gt)) * v);
        } else if (epi == 4) {
          Cb[idx] = f2b(v);
        } else if (epi == 8) {
          atomicAdd(&Cf[idx], v);
        } else {  // 7: rope -> q or k (block-uniform region)
          float sn, cs;
          __sincosf((float)(rowb + r) * invf, &sn, &cs);
          const unsigned short o = f2b(v * cs + sgn * p * sn);
          if (col < 2048)
            Cb[(size_t)(rowb + r) * 2048 + col] = o;
          else
            Cb2[(size_t)(rowb + r) * 512 + col - 2048] = o;
        }
      }
    }
}

// ---------------------------------------------------------------------------
// Flash attention, flash-decoding style (unchanged from round 4).
// ---------------------------------------------------------------------------
#define PSTR 136   // P row stride (bf16); 136*2=272 bytes, 16B-aligned
__global__ __launch_bounds__(256) void flash_attn(
    const unsigned short* __restrict__ Qb, const unsigned short* __restrict__ Kb,
    const unsigned short* __restrict__ Vt, unsigned short* __restrict__ Y,
    int T) {
  __shared__ char shmem[4 * 4352];   // 17408 B total

  const int tid = threadIdx.x;
  const int wave = tid >> 6, lane = tid & 63;
  const int quad = lane >> 4, l16 = lane & 15;
  const int h = blockIdx.y;
  const int qt = gridDim.x - 1 - blockIdx.x;   // longest-job-first
  const int kvh = h >> 2;
  const int qbase = qt * 16;

  short8 aQ[2];
#pragma unroll
  for (int c = 0; c < 2; ++c)
    aQ[c] = *(const short8*)(Qb + (size_t)(qbase + l16) * 2048 + h * 64 +
                             c * 32 + quad * 8);

  float m_i[4], l_i[4];
  f32x4 Oacc[4] = {};
#pragma unroll
  for (int r = 0; r < 4; ++r) { m_i[r] = -1e30f; l_i[r] = 0.f; }

  unsigned short* Pw = (unsigned short*)(shmem + wave * 4352);
  const int nchunk = (qbase + 16 + 127) >> 7;   // keys 0 .. qbase+15

  for (int jt = wave; jt < nchunk; jt += 4) {
    const int k0 = jt << 7;
    f32x4 S[8];
#pragma unroll
    for (int s = 0; s < 8; ++s) {
      const size_t kr = (size_t)(k0 + s * 16 + l16) * 512 + kvh * 64;
      const short8 b0 = *(const short8*)(Kb + kr + quad * 8);
      const short8 b1 = *(const short8*)(Kb + kr + 32 + quad * 8);
      f32x4 z = {};
      z = __builtin_amdgcn_mfma_f32_16x16x32_bf16(aQ[0], b0, z, 0, 0, 0);
      z = __builtin_amdgcn_mfma_f32_16x16x32_bf16(aQ[1], b1, z, 0, 0, 0);
      S[s] = z;
    }
    float tmax[4];
#pragma unroll
    for (int r = 0; r < 4; ++r) {
      const int qrow = qbase + quad * 4 + r;
      float mx = -3e38f;
#pragma unroll
      for (int s = 0; s < 8; ++s) {
        const int key = k0 + s * 16 + l16;
        float v = S[s][r] * 0.125f;
        if (key > qrow) v = -3e38f;
        S[s][r] = v;
        mx = fmaxf(mx, v);
      }
      tmax[r] = mx;
    }
#pragma unroll
    for (int off = 1; off < 16; off <<= 1)
#pragma unroll
      for (int r = 0; r < 4; ++r)
        tmax[r] = fmaxf(tmax[r], __shfl_xor(tmax[r], off, 64));

    float alpha[4], rsum[4];
#pragma unroll
    for (int r = 0; r < 4; ++r) {
      const float mn = fmaxf(m_i[r], tmax[r]);
      alpha[r] = __expf(m_i[r] - mn);
      m_i[r] = mn;
      float acc = 0.f;
#pragma unroll
      for (int s = 0; s < 8; ++s) {
        const float p = __expf(S[s][r] - mn);
        S[s][r] = p;
        acc += p;
      }
      rsum[r] = acc;
    }
#pragma unroll
    for (int off = 1; off < 16; off <<= 1)
#pragma unroll
      for (int r = 0; r < 4; ++r)
        rsum[r] += __shfl_xor(rsum[r], off, 64);
#pragma unroll
    for (int r = 0; r < 4; ++r) l_i[r] = l_i[r] * alpha[r] + rsum[r];

#pragma unroll
    for (int s = 0; s < 8; ++s)
#pragma unroll
      for (int r = 0; r < 4; ++r)
        Pw[(quad * 4 + r) * PSTR + s * 16 + l16] = f2b(S[s][r]);
    __threadfence_block();
    short8 aP[4];
#pragma unroll
    for (int kc = 0; kc < 4; ++kc)
      aP[kc] = *(const short8*)(Pw + l16 * PSTR + kc * 32 + quad * 8);

#pragma unroll
    for (int c = 0; c < 4; ++c)
#pragma unroll
      for (int r = 0; r < 4; ++r) Oacc[c][r] *= alpha[r];
#pragma unroll
    for (int c = 0; c < 4; ++c) {
      const size_t vr = (size_t)(kvh * 64 + c * 16 + l16) * T + k0;
#pragma unroll
      for (int kc = 0; kc < 4; ++kc) {
        const short8 bV = *(const short8*)(Vt + vr + kc * 32 + quad * 8);
        Oacc[c] = __builtin_amdgcn_mfma_f32_16x16x32_bf16(aP[kc], bV,
                                                          Oacc[c], 0, 0, 0);
      }
    }
  }

  float* OWw = (float*)(shmem + wave * 4352);          // [c][row][l16]
  float* mw  = (float*)(shmem + wave * 4352 + 4096);
  float* lw  = (float*)(shmem + wave * 4352 + 4160);
#pragma unroll
  for (int c = 0; c < 4; ++c)
#pragma unroll
    for (int r = 0; r < 4; ++r)
      OWw[c * 256 + (quad * 4 + r) * 16 + l16] = Oacc[c][r];
  if (l16 == 0)
#pragma unroll
    for (int r = 0; r < 4; ++r) {
      mw[quad * 4 + r] = m_i[r];
      lw[quad * 4 + r] = l_i[r];
    }
  __syncthreads();

  const int c = wave;
#pragma unroll
  for (int r = 0; r < 4; ++r) {
    const int row = quad * 4 + r;
    float M = -3e38f;
#pragma unroll
    for (int w2 = 0; w2 < 4; ++w2)
      M = fmaxf(M, ((const float*)(shmem + w2 * 4352 + 4096))[row]);
    float num = 0.f, den = 0.f;
#pragma unroll
    for (int w2 = 0; w2 < 4; ++w2) {
      const float mv = ((const float*)(shmem + w2 * 4352 + 4096))[row];
      const float lv = ((const float*)(shmem + w2 * 4352 + 4160))[row];
      const float sc = __expf(mv - M);
      den += lv * sc;
      num += ((const float*)(shmem + w2 * 4352))[c * 256 + row * 16 + l16] * sc;
    }
    Y[(size_t)(qbase + row) * 2048 + h * 64 + c * 16 + l16] = f2b(num / den);
  }
}

// ---------------------------------------------------------------------------
extern "C" void kernel_launch(void* const* d_in, const int* in_sizes, int n_in,
                              void* d_out, int out_size, void* d_ws,
                              size_t ws_size, hipStream_t stream) {
  const float* x  = (const float*)d_in[0];
  const float* g1 = (const float*)d_in[1];
  const float* wq = (const float*)d_in[2];
  const float* wk = (const float*)d_in[3];
  const float* wv = (const float*)d_in[4];
  const float* wo = (const float*)d_in[5];
  const float* g2 = (const float*)d_in[6];
  const float* wg = (const float*)d_in[7];
  const float* wu = (const float*)d_in[8];
  const float* wd = (const float*)d_in[9];
  float* out = (float*)d_out;

  const int T = 2048, Dm = 2048, FF = 8192;
  char* ws = (char*)d_ws;
  const size_t MB = (size_t)1 << 20;

  unsigned short* wq_t = (unsigned short*)(ws + 0 * MB);    // 8 MB  } contig
  unsigned short* wk_t = (unsigned short*)(ws + 8 * MB);    // 2 MB  } rows
  unsigned short* wv_t = (unsigned short*)(ws + 10 * MB);   // 2 MB  } 0..3071
  unsigned short* wo_t = (unsigned short*)(ws + 12 * MB);   // 8 MB
  unsigned short* wg_t = (unsigned short*)(ws + 20 * MB);   // 32 MB
  unsigned short* wu_t = (unsigned short*)(ws + 52 * MB);   // 32 MB
  unsigned short* h1_b = (unsigned short*)(ws + 84 * MB);   // 8 MB
  unsigned short* h2_b = (unsigned short*)(ws + 92 * MB);   // 8 MB
  float*          x2_f = (float*)(ws + 100 * MB);           // 16 MB (dies early)
  unsigned short* gate = (unsigned short*)(ws + 100 * MB);  // 32 MB (in-place)
  unsigned short* q_b  = (unsigned short*)(ws + 132 * MB);  // 8 MB
  unsigned short* k_b  = (unsigned short*)(ws + 140 * MB);  // 2 MB
  unsigned short* vt_b = (unsigned short*)(ws + 142 * MB);  // 2 MB
  unsigned short* y_b  = (unsigned short*)(ws + 144 * MB);  // 8 MB
  unsigned short* wd_t = (unsigned short*)(ws + 132 * MB);  // 32 MB (after attn)

  // 1. Weight cast+transpose (wd deferred until attn scratch is dead).
  transpose_cast<<<dim3(64, 64), 256, 0, stream>>>(wq, wq_t, Dm, Dm);
  transpose_cast<<<dim3(16, 64), 256, 0, stream>>>(wk, wk_t, Dm, 512);
  transpose_cast<<<dim3(16, 64), 256, 0, stream>>>(wv, wv_t, Dm, 512);
  transpose_cast<<<dim3(64, 64), 256, 0, stream>>>(wo, wo_t, Dm, Dm);
  transpose_cast<<<dim3(256, 64), 256, 0, stream>>>(wg, wg_t, Dm, FF);
  transpose_cast<<<dim3(256, 64), 256, 0, stream>>>(wu, wu_t, Dm, FF);

  // 2. h1 = rms(x0)
  rmsnorm<<<T, 256, 0, stream>>>(x, g1, h1_b);

  // 3. Fused QKV projection (N=3072): rope q -> q_b, rope k -> k_b,
  //    transposed v -> vt_b.
  gemm_bt<<<dim3(24, 16), 256, 0, stream>>>(h1_b, wq_t, nullptr, q_b, nullptr,
                                            nullptr, 3072, Dm, Dm, 7, T, k_b,
                                            vt_b);

  // 4. Attention (4 waves/block, key-split, LJF).
  flash_attn<<<dim3(T / 16, 32), 256, 0, stream>>>(q_b, k_b, vt_b, y_b, T);

  // 5. x2 = h1 + y @ wo  (epi 1).
  gemm_bt<<<dim3(16, 16), 256, 0, stream>>>(y_b, wo_t, x2_f, nullptr, h1_b,
                                            nullptr, Dm, Dm, Dm, 1, 0, nullptr,
                                            nullptr);

  // 6. wd transpose into the now-dead attention scratch.
  transpose_cast<<<dim3(64, 256), 256, 0, stream>>>(wd, wd_t, FF, Dm);

  // 7. h2 = rms(x2)
  rmsnorm<<<T, 256, 0, stream>>>(x2_f, g2, h2_b);

  // 8. MLP: gate (epi 4), then up fused with silu in-place (epi 3).
  gemm_bt<<<dim3(64, 16), 256, 0, stream>>>(h2_b, wg_t, nullptr, gate, nullptr,
                                            nullptr, FF, Dm, Dm, 4, 0, nullptr,
                                            nullptr);
  gemm_bt<<<dim3(64, 16), 256, 0, stream>>>(h2_b, wu_t, nullptr, gate, gate,
                                            nullptr, FF, Dm, Dm, 3, 0, nullptr,
                                            nullptr);

  // 9. out = h2 + x0 (pre-fill), then split-K x4 down-proj atomicAdd.
  add_res<<<(T * Dm / 4) / 256, 256, 0, stream>>>(h2_b, x, out);
  gemm_bt<<<dim3(16, 16, 4), 256, 0, stream>>>(gate, wd_t, out, nullptr,
                                               nullptr, nullptr, Dm, FF,
                                               FF / 4, 8, 0, nullptr, nullptr);
}